// Round 19
// baseline (151.377 us; speedup 1.0000x reference)
//
#include <hip/hip_runtime.h>

// Round 19 (attn only; GEMMs/cvt3/prefill frozen from R18):
//   1) QK accumulator split: s_a(ks0,1) || s_b(ks2,3), merged with 8
//      v_pk_add_f32 — dependent MFMA chain 4 -> 2 (~68 cy/tile).
//   2) ts computed as explicit 4-level tree (fp adds are source-ordered;
//      serial chain 15 -> 4 adds, ~45 cy/tile).
// Constants: B=8 N=1024 C=768 H=12 D=64 P=16; BH=96; padded KV MKV=1056.

typedef __attribute__((ext_vector_type(8))) short short8;
typedef __attribute__((ext_vector_type(4))) float f32x4;
typedef __attribute__((ext_vector_type(16))) float f32x16;
typedef __attribute__((ext_vector_type(4))) int i32x4;

#define GLOAD_LDS16(g, l)                                              \
    __builtin_amdgcn_global_load_lds(                                  \
        (const __attribute__((address_space(1))) void*)(g),            \
        (__attribute__((address_space(3))) void*)(l), 16, 0, 0)

#define GBAR  asm volatile("s_barrier" ::: "memory")
#define LGKM0 asm volatile("s_waitcnt lgkmcnt(0)" ::: "memory")
#define VMC4  asm volatile("s_waitcnt vmcnt(4)" ::: "memory")
#define VMC0  asm volatile("s_waitcnt vmcnt(0)" ::: "memory")
#define PSWAP(a, b) asm("v_permlane32_swap_b32 %0, %1" : "+v"(a), "+v"(b))

__device__ __forceinline__ unsigned short f2b(float f) {
    unsigned u = __builtin_bit_cast(unsigned, f);
    u = (u + 0x7fffu + ((u >> 16) & 1u)) >> 16;
    return (unsigned short)u;
}

__device__ __forceinline__ int cvt_pk_bf16(float lo, float hi) {
    int r;
    asm("v_cvt_pk_bf16_f32 %0, %1, %2" : "=v"(r) : "v"(lo), "v"(hi));
    return r;
}

__device__ __forceinline__ float fexp2(float x) {
    float r;
    asm("v_exp_f32 %0, %1" : "=v"(r) : "v"(x));
    return r;
}

// ---------- fused f32 -> bf16 convert for x, qkv_w, proj_w (1 launch) ----------
__global__ void cvt3(const float* __restrict__ a, unsigned short* __restrict__ ao, int na4,
                     const float* __restrict__ b, unsigned short* __restrict__ bo, int nb4,
                     const float* __restrict__ c, unsigned short* __restrict__ co, int nc4) {
    int total = na4 + nb4 + nc4;
    int i = blockIdx.x * blockDim.x + threadIdx.x;
    int stride = gridDim.x * blockDim.x;
    for (; i < total; i += stride) {
        const float* src; unsigned short* dst; int j;
        if (i < na4)            { src = a; dst = ao; j = i; }
        else if (i < na4 + nb4) { src = b; dst = bo; j = i - na4; }
        else                    { src = c; dst = co; j = i - na4 - nb4; }
        float4 v = reinterpret_cast<const float4*>(src)[j];
        ushort4 o;
        o.x = f2b(v.x); o.y = f2b(v.y); o.z = f2b(v.z); o.w = f2b(v.w);
        reinterpret_cast<ushort4*>(dst)[j] = o;
    }
}

// ------------- prefix K/V prefill + pad-row zeroing ----------------
__global__ void prefill(const float* __restrict__ pk, const float* __restrict__ pv,
                        unsigned short* __restrict__ kc, unsigned short* __restrict__ vT) {
    int idx = blockIdx.x * 256 + threadIdx.x;   // 96*32*64 total
    int d  = idx & 63;
    int j  = (idx >> 6) & 31;
    int bh = idx >> 11;
    if (bh >= 96) return;
    int h = bh % 12;
    if (j < 16) {
        kc[((size_t)bh * 1056 + j) * 64 + d]  = f2b(pk[j * 768 + h * 64 + d]);
        vT[((size_t)bh * 64 + d) * 1056 + j]  = f2b(pv[j * 768 + h * 64 + d]);
    } else {
        int row = 1040 + (j - 16);
        kc[((size_t)bh * 1056 + row) * 64 + d] = 0;
        vT[((size_t)bh * 64 + d) * 1056 + row] = 0;
    }
}

// ------- GEMM: BK=32 ring-3, counted vmcnt(4), 48KB LDS, 3 blocks/CU -------
template<int MODE, int FT>
__global__ __launch_bounds__(256, 3) void gemm_dp(
    const unsigned short* __restrict__ A,
    const unsigned short* __restrict__ W,
    const float* __restrict__ bias,
    int M, int F, int K,
    unsigned short* __restrict__ qbuf,
    unsigned short* __restrict__ kcbuf,
    unsigned short* __restrict__ vtbuf,
    float* __restrict__ fout)
{
    __shared__ __align__(16) unsigned short SH[24576];   // 48KB
#define AS_(s) (SH + (s) * 4096)
#define BS_(s) (SH + 12288 + (s) * 4096)

    const int tid = threadIdx.x;
    const int bid = (blockIdx.x & 7) * (gridDim.x >> 3) + (blockIdx.x >> 3);
    const int m0 = (bid / FT) * 128;
    const int f0 = (bid % FT) * 128;
    const int wid = tid >> 6, lane = tid & 63;
    const int wr = wid >> 1, wc = wid & 1;
    const int lo = lane & 15, hi = lane >> 4;
    const int rdsw = ((hi ^ (lo & 3)) << 4);

#define STG(SLOT, KT)                                                            \
    { _Pragma("unroll") for (int r_ = 0; r_ < 2; ++r_) {                         \
        int id_ = r_ * 256 + tid; int row_ = id_ >> 2;                           \
        int sc_ = (((id_ & 3) ^ (row_ & 3)) << 3);                               \
        GLOAD_LDS16(A + (size_t)(m0 + row_) * K + (KT) * 32 + sc_,               \
                    (char*)AS_(SLOT) + id_ * 16);                                \
        GLOAD_LDS16(W + (size_t)(f0 + row_) * K + (KT) * 32 + sc_,               \
                    (char*)BS_(SLOT) + id_ * 16);                                \
    } }

    f32x4 acc[4][4];
#pragma unroll
    for (int i = 0; i < 4; ++i)
#pragma unroll
        for (int j = 0; j < 4; ++j) acc[i][j] = (f32x4)0.f;

    const int nt = K >> 5;   // 24

    STG(0, 0);
    STG(1, 1);
    VMC4; GBAR;

    int slot = 0, nslot = 2;
    for (int t = 0; t < nt; ++t) {
        if (t + 2 < nt) {
            STG(nslot, t + 2);
            nslot = (nslot == 2) ? 0 : nslot + 1;
        }

        short8 av[4], bv[4];
#pragma unroll
        for (int i = 0; i < 4; ++i) {
            av[i] = *reinterpret_cast<const short8*>(
                (const char*)AS_(slot) + (wr * 64 + i * 16 + lo) * 64 + rdsw);
            bv[i] = *reinterpret_cast<const short8*>(
                (const char*)BS_(slot) + (wc * 64 + i * 16 + lo) * 64 + rdsw);
        }
        slot = (slot == 2) ? 0 : slot + 1;

        __builtin_amdgcn_s_setprio(1);
#pragma unroll
        for (int i = 0; i < 4; ++i)
#pragma unroll
            for (int j = 0; j < 4; ++j)
                acc[i][j] = __builtin_amdgcn_mfma_f32_16x16x32_bf16(
                    av[i], bv[j], acc[i][j], 0, 0, 0);
        __builtin_amdgcn_s_setprio(0);

        if (t + 1 < nt) {
            if (t + 2 < nt) { VMC4; }
            else            { VMC0; }
            GBAR;
        }
    }

    if (MODE == 1) {
#pragma unroll
        for (int mi = 0; mi < 4; ++mi) {
#pragma unroll
            for (int ni = 0; ni < 4; ++ni) {
                int f = f0 + wc * 64 + ni * 16 + lo;
                float bv2 = bias[f];
#pragma unroll
                for (int r = 0; r < 4; ++r) {
                    int m = m0 + wr * 64 + mi * 16 + hi * 4 + r;
                    fout[(size_t)m * F + f] = acc[mi][ni][r] + bv2;
                }
            }
        }
    } else {
        __syncthreads();
        // Q scale = D^-0.5 * log2(e): QK^T emits log2-domain scores (static softmax)
        const float sc = (f0 < 768) ? 0.1803368801111204f : 1.f;
#pragma unroll
        for (int mi = 0; mi < 4; ++mi) {
#pragma unroll
            for (int ni = 0; ni < 4; ++ni) {
                int fc = wc * 64 + ni * 16 + lo;
                float bv2 = bias[f0 + fc];
#pragma unroll
                for (int r = 0; r < 4; ++r) {
                    int mr = wr * 64 + mi * 16 + hi * 4 + r;
                    SH[mr * 136 + fc] = f2b((acc[mi][ni][r] + bv2) * sc);
                }
            }
        }
        __syncthreads();

        const int row2 = tid >> 1, half = tid & 1;
        const int b_ = m0 >> 10, n0 = m0 & 1023;
        if (f0 < 1536) {
            const unsigned short* src = SH + row2 * 136 + half * 64;
            unsigned short* dst;
            if (f0 < 768) {
                int h = (f0 >> 6) + half;
                dst = qbuf + (((size_t)(b_ * 12 + h) * 1024 + n0 + row2) << 6);
            } else {
                int h = ((f0 - 768) >> 6) + half;
                dst = kcbuf + (((size_t)(b_ * 12 + h) * 1056 + 16 + n0 + row2) << 6);
            }
#pragma unroll
            for (int c = 0; c < 8; ++c)
                *reinterpret_cast<short8*>(dst + c * 8) =
                    *reinterpret_cast<const short8*>(src + c * 8);
        } else {
            int fv = f0 - 1536 + row2;
            int h = fv >> 6, d = fv & 63;
            unsigned short* dst = vtbuf + ((size_t)(b_ * 12 + h) * 64 + d) * 1056
                                  + 16 + n0 + half * 64;
#pragma unroll
            for (int c = 0; c < 8; ++c) {
                short8 v;
#pragma unroll
                for (int j = 0; j < 8; ++j)
                    v[j] = (short)SH[(half * 64 + c * 8 + j) * 136 + row2];
                *reinterpret_cast<short8*>(dst + c * 8) = v;
            }
        }
    }
#undef STG
#undef AS_
#undef BS_
}

// -------- flash attention: swapped-QK 32x32, K async-LDS dbuf, static softmax --------
__global__ __launch_bounds__(256) void attn_kernel(
    const unsigned short* __restrict__ q,   // [96][1024][64] (pre-scaled by D^-0.5*log2e)
    const unsigned short* __restrict__ kc,  // [96][1056][64]
    const unsigned short* __restrict__ vT,  // [96][64][1056]
    unsigned short* __restrict__ ao)        // [8][1024][768]
{
    __shared__ __align__(16) unsigned short OT[4][32 * 72];   // epilogue bounce
    __shared__ __align__(16) unsigned short KS[4][2][2048];   // per-wave K dbuf

    const int tid = threadIdx.x;
    const int w = tid >> 6, lane = tid & 63;
    const int ql = lane & 31;
    const int hi = lane >> 5;

    const int bid = (blockIdx.x & 7) * 96 + (blockIdx.x >> 3);
    const int head = bid >> 3;
    const int qt = (bid & 7) * 4 + w;
    const int b = head / 12, h = head % 12;

    const unsigned short* qp = q + ((size_t)head * 1024 + qt * 32) * 64;
    const unsigned short* kp = kc + (size_t)head * 1056 * 64;
    const unsigned short* vp = vT + (size_t)head * 64 * 1056;

    const int srow = lane >> 3;
    const int sce  = ((lane & 7) ^ srow) << 3;
    const int rsw  = (ql & 7) << 4;

    short8 qf[4];
#pragma unroll
    for (int ks = 0; ks < 4; ++ks)
        qf[ks] = *reinterpret_cast<const short8*>(qp + (size_t)ql * 64 + ks * 16 + hi * 8);

    // prologue: stage K tile 0
#pragma unroll
    for (int i = 0; i < 4; ++i)
        GLOAD_LDS16(kp + (size_t)(i * 8 + srow) * 64 + sce,
                    (char*)&KS[w][0][0] + i * 1024);

    f32x16 o0 = (f32x16)0.f, o1 = (f32x16)0.f;
    const f32x16 fz = (f32x16)0.f;      // persistent zero C-operand
    float l = 0.f;

    for (int t = 0; t < 33; ++t) {
        const int kbase = t * 32;
        const char* kcur = (const char*)&KS[w][t & 1][0];

        if (t < 32) {
            char* knx = (char*)&KS[w][(t & 1) ^ 1][0];
            const unsigned short* ksrc = kp + (size_t)(kbase + 32) * 64;
#pragma unroll
            for (int i = 0; i < 4; ++i)
                GLOAD_LDS16(ksrc + (size_t)(i * 8 + srow) * 64 + sce, knx + i * 1024);
            asm volatile("s_waitcnt vmcnt(4)" ::: "memory");
        } else {
            asm volatile("s_waitcnt vmcnt(0)" ::: "memory");
        }

        // ---- S^T = K·Q^T: two independent 2-deep MFMA chains, merged ----
        f32x16 sa, sb;
        __builtin_amdgcn_s_setprio(1);
        {
            short8 kf0 = *reinterpret_cast<const short8*>(kcur + ql * 128 + ((hi * 16) ^ rsw));
            short8 kf2 = *reinterpret_cast<const short8*>(kcur + ql * 128 + ((64 + hi * 16) ^ rsw));
            sa = __builtin_amdgcn_mfma_f32_32x32x16_bf16(kf0, qf[0], fz, 0, 0, 0);
            sb = __builtin_amdgcn_mfma_f32_32x32x16_bf16(kf2, qf[2], fz, 0, 0, 0);
            short8 kf1 = *reinterpret_cast<const short8*>(kcur + ql * 128 + ((32 + hi * 16) ^ rsw));
            short8 kf3 = *reinterpret_cast<const short8*>(kcur + ql * 128 + ((96 + hi * 16) ^ rsw));
            sa = __builtin_amdgcn_mfma_f32_32x32x16_bf16(kf1, qf[1], sa, 0, 0, 0);
            sb = __builtin_amdgcn_mfma_f32_32x32x16_bf16(kf3, qf[3], sb, 0, 0, 0);
        }
        __builtin_amdgcn_s_setprio(0);
        f32x16 s = sa + sb;              // 8 v_pk_add_f32

        if (t == 32) {   // keys 1040..1055 invalid -> regs 8..15
#pragma unroll
            for (int r = 8; r < 16; ++r) s[r] = -1e30f;
        }

        // ---- static softmax: p = 2^s via raw v_exp_f32; tree-summed ts ----
        float p[16];
#pragma unroll
        for (int r = 0; r < 16; ++r) p[r] = fexp2(s[r]);
        float t0 = (p[0] + p[1]) + (p[2] + p[3]);
        float t1 = (p[4] + p[5]) + (p[6] + p[7]);
        float t2 = (p[8] + p[9]) + (p[10] + p[11]);
        float t3 = (p[12] + p[13]) + (p[14] + p[15]);
        l += (t0 + t1) + (t2 + t3);

        // ---- P -> bf16 B-fragments: cvt_pk + permlane32_swap ----
        int w0 = cvt_pk_bf16(p[0],  p[1]),  w1 = cvt_pk_bf16(p[2],  p[3]);
        int w2 = cvt_pk_bf16(p[4],  p[5]),  w3 = cvt_pk_bf16(p[6],  p[7]);
        int w4 = cvt_pk_bf16(p[8],  p[9]),  w5 = cvt_pk_bf16(p[10], p[11]);
        int w6 = cvt_pk_bf16(p[12], p[13]), w7 = cvt_pk_bf16(p[14], p[15]);
        PSWAP(w0, w2); PSWAP(w1, w3); PSWAP(w4, w6); PSWAP(w5, w7);
        i32x4 pw0, pw1;
        pw0[0] = w0; pw0[1] = w1; pw0[2] = w2; pw0[3] = w3;
        pw1[0] = w4; pw1[1] = w5; pw1[2] = w6; pw1[3] = w7;
        short8 pf0 = __builtin_bit_cast(short8, pw0);
        short8 pf1 = __builtin_bit_cast(short8, pw1);

        // ---- O^T += V^T · P^T (4 mfma), V direct from global ----
        short8 vf00 = *reinterpret_cast<const short8*>(vp + (size_t)ql * 1056 + kbase + hi * 8);
        short8 vf01 = *reinterpret_cast<const short8*>(vp + (size_t)ql * 1056 + kbase + 16 + hi * 8);
        short8 vf10 = *reinterpret_cast<const short8*>(vp + (size_t)(32 + ql) * 1056 + kbase + hi * 8);
        short8 vf11 = *reinterpret_cast<const short8*>(vp + (size_t)(32 + ql) * 1056 + kbase + 16 + hi * 8);
        __builtin_amdgcn_s_setprio(1);
        o0 = __builtin_amdgcn_mfma_f32_32x32x16_bf16(vf00, pf0, o0, 0, 0, 0);
        o0 = __builtin_amdgcn_mfma_f32_32x32x16_bf16(vf01, pf1, o0, 0, 0, 0);
        o1 = __builtin_amdgcn_mfma_f32_32x32x16_bf16(vf10, pf0, o1, 0, 0, 0);
        o1 = __builtin_amdgcn_mfma_f32_32x32x16_bf16(vf11, pf1, o1, 0, 0, 0);
        __builtin_amdgcn_s_setprio(0);
    }

    // ---- cross-half l reduce (deferred), then epilogue bounce ----
    l += __shfl_xor(l, 32);
    const float rinv = 1.f / l;
    o0 *= rinv;
    o1 *= rinv;
    unsigned short* ow = &OT[w][0];
#pragma unroll
    for (int r = 0; r < 16; r += 2) {
        int d = (r & 3) + 8 * (r >> 2) + 4 * hi;
        unsigned v0 = (unsigned)f2b(o0[r]) | ((unsigned)f2b(o0[r + 1]) << 16);
        *reinterpret_cast<unsigned*>(ow + ql * 72 + d) = v0;
        unsigned v1 = (unsigned)f2b(o1[r]) | ((unsigned)f2b(o1[r + 1]) << 16);
        *reinterpret_cast<unsigned*>(ow + ql * 72 + 32 + d) = v1;
    }
    LGKM0;
    __builtin_amdgcn_sched_barrier(0);
    const int row2 = lane >> 1, half = lane & 1;
    unsigned short* dst = ao + ((size_t)b * 1024 + qt * 32 + row2) * 768 + h * 64 + half * 32;
    const unsigned short* src = ow + row2 * 72 + half * 32;
#pragma unroll
    for (int c = 0; c < 4; ++c)
        *reinterpret_cast<short8*>(dst + c * 8) =
            *reinterpret_cast<const short8*>(src + c * 8);
}

extern "C" void kernel_launch(void* const* d_in, const int* in_sizes, int n_in,
                              void* d_out, int out_size, void* d_ws, size_t ws_size,
                              hipStream_t stream) {
    const float* x        = (const float*)d_in[0];
    const float* qkv_w    = (const float*)d_in[1];
    const float* qkv_b    = (const float*)d_in[2];
    const float* proj_w   = (const float*)d_in[3];
    const float* proj_b   = (const float*)d_in[4];
    const float* prefix_k = (const float*)d_in[5];
    const float* prefix_v = (const float*)d_in[6];
    float* out = (float*)d_out;

    char* ws = (char*)d_ws;
    unsigned short* xb   = (unsigned short*)(ws);               // 8192*768 bf16
    unsigned short* wqkv = (unsigned short*)(ws + 12582912);    // 2304*768
    unsigned short* wp   = (unsigned short*)(ws + 16121856);    // 768*768
    unsigned short* qb   = (unsigned short*)(ws + 17301504);    // 96*1024*64
    unsigned short* kcb  = (unsigned short*)(ws + 29884416);    // 96*1056*64
    unsigned short* vtb  = (unsigned short*)(ws + 42860544);    // 96*64*1056
    unsigned short* aob  = xb;                                  // reuse xb after QKV GEMM

    // fused converts: x (1572864 f4), qkv_w (442368 f4), proj_w (147456 f4)
    cvt3<<<2048, 256, 0, stream>>>(x, xb, 1572864, qkv_w, wqkv, 442368,
                                   proj_w, wp, 147456);
    prefill<<<768, 256, 0, stream>>>(prefix_k, prefix_v, kcb, vtb);

    // QKV: 64 m-tiles x 18 f-tiles = 1152 blocks (1152%8==0)
    gemm_dp<0, 18><<<1152, 256, 0, stream>>>(xb, wqkv, qkv_b, 8192, 2304, 768,
                                             qb, kcb, vtb, nullptr);
    attn_kernel<<<768, 256, 0, stream>>>(qb, kcb, vtb, aob);
    // proj: 64 m-tiles x 6 f-tiles = 384 blocks (384%8==0)
    gemm_dp<1, 6><<<384, 256, 0, stream>>>(aob, wp, proj_b, 8192, 768, 768,
                                           nullptr, nullptr, nullptr, out);
}

// Round 20
// 128.922 us; speedup vs baseline: 1.1742x; 1.1742x over previous
//
#include <hip/hip_runtime.h>

// Round 20: FULL REVERT to the R18 best (128.6us). R19's split-accumulator
// raised VGPR 68->92 -> occupancy 27.5->16% -> attn 60->84us (third attn
// register-pressure cliff this session: R9, R17, R19). No new experiment —
// clean re-establish of best-known state.
// Constants: B=8 N=1024 C=768 H=12 D=64 P=16; BH=96; padded KV MKV=1056.

typedef __attribute__((ext_vector_type(8))) short short8;
typedef __attribute__((ext_vector_type(4))) float f32x4;
typedef __attribute__((ext_vector_type(16))) float f32x16;
typedef __attribute__((ext_vector_type(4))) int i32x4;

#define GLOAD_LDS16(g, l)                                              \
    __builtin_amdgcn_global_load_lds(                                  \
        (const __attribute__((address_space(1))) void*)(g),            \
        (__attribute__((address_space(3))) void*)(l), 16, 0, 0)

#define GBAR  asm volatile("s_barrier" ::: "memory")
#define LGKM0 asm volatile("s_waitcnt lgkmcnt(0)" ::: "memory")
#define VMC4  asm volatile("s_waitcnt vmcnt(4)" ::: "memory")
#define VMC0  asm volatile("s_waitcnt vmcnt(0)" ::: "memory")
#define PSWAP(a, b) asm("v_permlane32_swap_b32 %0, %1" : "+v"(a), "+v"(b))

__device__ __forceinline__ unsigned short f2b(float f) {
    unsigned u = __builtin_bit_cast(unsigned, f);
    u = (u + 0x7fffu + ((u >> 16) & 1u)) >> 16;
    return (unsigned short)u;
}

__device__ __forceinline__ int cvt_pk_bf16(float lo, float hi) {
    int r;
    asm("v_cvt_pk_bf16_f32 %0, %1, %2" : "=v"(r) : "v"(lo), "v"(hi));
    return r;
}

__device__ __forceinline__ float fexp2(float x) {
    float r;
    asm("v_exp_f32 %0, %1" : "=v"(r) : "v"(x));
    return r;
}

// ---------- fused f32 -> bf16 convert for x, qkv_w, proj_w (1 launch) ----------
__global__ void cvt3(const float* __restrict__ a, unsigned short* __restrict__ ao, int na4,
                     const float* __restrict__ b, unsigned short* __restrict__ bo, int nb4,
                     const float* __restrict__ c, unsigned short* __restrict__ co, int nc4) {
    int total = na4 + nb4 + nc4;
    int i = blockIdx.x * blockDim.x + threadIdx.x;
    int stride = gridDim.x * blockDim.x;
    for (; i < total; i += stride) {
        const float* src; unsigned short* dst; int j;
        if (i < na4)            { src = a; dst = ao; j = i; }
        else if (i < na4 + nb4) { src = b; dst = bo; j = i - na4; }
        else                    { src = c; dst = co; j = i - na4 - nb4; }
        float4 v = reinterpret_cast<const float4*>(src)[j];
        ushort4 o;
        o.x = f2b(v.x); o.y = f2b(v.y); o.z = f2b(v.z); o.w = f2b(v.w);
        reinterpret_cast<ushort4*>(dst)[j] = o;
    }
}

// ------------- prefix K/V prefill + pad-row zeroing ----------------
__global__ void prefill(const float* __restrict__ pk, const float* __restrict__ pv,
                        unsigned short* __restrict__ kc, unsigned short* __restrict__ vT) {
    int idx = blockIdx.x * 256 + threadIdx.x;   // 96*32*64 total
    int d  = idx & 63;
    int j  = (idx >> 6) & 31;
    int bh = idx >> 11;
    if (bh >= 96) return;
    int h = bh % 12;
    if (j < 16) {
        kc[((size_t)bh * 1056 + j) * 64 + d]  = f2b(pk[j * 768 + h * 64 + d]);
        vT[((size_t)bh * 64 + d) * 1056 + j]  = f2b(pv[j * 768 + h * 64 + d]);
    } else {
        int row = 1040 + (j - 16);
        kc[((size_t)bh * 1056 + row) * 64 + d] = 0;
        vT[((size_t)bh * 64 + d) * 1056 + row] = 0;
    }
}

// ------- GEMM: BK=32 ring-3, counted vmcnt(4), 48KB LDS, 3 blocks/CU -------
template<int MODE, int FT>
__global__ __launch_bounds__(256, 3) void gemm_dp(
    const unsigned short* __restrict__ A,
    const unsigned short* __restrict__ W,
    const float* __restrict__ bias,
    int M, int F, int K,
    unsigned short* __restrict__ qbuf,
    unsigned short* __restrict__ kcbuf,
    unsigned short* __restrict__ vtbuf,
    float* __restrict__ fout)
{
    __shared__ __align__(16) unsigned short SH[24576];   // 48KB
#define AS_(s) (SH + (s) * 4096)
#define BS_(s) (SH + 12288 + (s) * 4096)

    const int tid = threadIdx.x;
    const int bid = (blockIdx.x & 7) * (gridDim.x >> 3) + (blockIdx.x >> 3);
    const int m0 = (bid / FT) * 128;
    const int f0 = (bid % FT) * 128;
    const int wid = tid >> 6, lane = tid & 63;
    const int wr = wid >> 1, wc = wid & 1;
    const int lo = lane & 15, hi = lane >> 4;
    const int rdsw = ((hi ^ (lo & 3)) << 4);

#define STG(SLOT, KT)                                                            \
    { _Pragma("unroll") for (int r_ = 0; r_ < 2; ++r_) {                         \
        int id_ = r_ * 256 + tid; int row_ = id_ >> 2;                           \
        int sc_ = (((id_ & 3) ^ (row_ & 3)) << 3);                               \
        GLOAD_LDS16(A + (size_t)(m0 + row_) * K + (KT) * 32 + sc_,               \
                    (char*)AS_(SLOT) + id_ * 16);                                \
        GLOAD_LDS16(W + (size_t)(f0 + row_) * K + (KT) * 32 + sc_,               \
                    (char*)BS_(SLOT) + id_ * 16);                                \
    } }

    f32x4 acc[4][4];
#pragma unroll
    for (int i = 0; i < 4; ++i)
#pragma unroll
        for (int j = 0; j < 4; ++j) acc[i][j] = (f32x4)0.f;

    const int nt = K >> 5;   // 24

    STG(0, 0);
    STG(1, 1);
    VMC4; GBAR;

    int slot = 0, nslot = 2;
    for (int t = 0; t < nt; ++t) {
        if (t + 2 < nt) {
            STG(nslot, t + 2);
            nslot = (nslot == 2) ? 0 : nslot + 1;
        }

        short8 av[4], bv[4];
#pragma unroll
        for (int i = 0; i < 4; ++i) {
            av[i] = *reinterpret_cast<const short8*>(
                (const char*)AS_(slot) + (wr * 64 + i * 16 + lo) * 64 + rdsw);
            bv[i] = *reinterpret_cast<const short8*>(
                (const char*)BS_(slot) + (wc * 64 + i * 16 + lo) * 64 + rdsw);
        }
        slot = (slot == 2) ? 0 : slot + 1;

        __builtin_amdgcn_s_setprio(1);
#pragma unroll
        for (int i = 0; i < 4; ++i)
#pragma unroll
            for (int j = 0; j < 4; ++j)
                acc[i][j] = __builtin_amdgcn_mfma_f32_16x16x32_bf16(
                    av[i], bv[j], acc[i][j], 0, 0, 0);
        __builtin_amdgcn_s_setprio(0);

        if (t + 1 < nt) {
            if (t + 2 < nt) { VMC4; }
            else            { VMC0; }
            GBAR;
        }
    }

    if (MODE == 1) {
#pragma unroll
        for (int mi = 0; mi < 4; ++mi) {
#pragma unroll
            for (int ni = 0; ni < 4; ++ni) {
                int f = f0 + wc * 64 + ni * 16 + lo;
                float bv2 = bias[f];
#pragma unroll
                for (int r = 0; r < 4; ++r) {
                    int m = m0 + wr * 64 + mi * 16 + hi * 4 + r;
                    fout[(size_t)m * F + f] = acc[mi][ni][r] + bv2;
                }
            }
        }
    } else {
        __syncthreads();
        // Q scale = D^-0.5 * log2(e): QK^T emits log2-domain scores (static softmax)
        const float sc = (f0 < 768) ? 0.1803368801111204f : 1.f;
#pragma unroll
        for (int mi = 0; mi < 4; ++mi) {
#pragma unroll
            for (int ni = 0; ni < 4; ++ni) {
                int fc = wc * 64 + ni * 16 + lo;
                float bv2 = bias[f0 + fc];
#pragma unroll
                for (int r = 0; r < 4; ++r) {
                    int mr = wr * 64 + mi * 16 + hi * 4 + r;
                    SH[mr * 136 + fc] = f2b((acc[mi][ni][r] + bv2) * sc);
                }
            }
        }
        __syncthreads();

        const int row2 = tid >> 1, half = tid & 1;
        const int b_ = m0 >> 10, n0 = m0 & 1023;
        if (f0 < 1536) {
            const unsigned short* src = SH + row2 * 136 + half * 64;
            unsigned short* dst;
            if (f0 < 768) {
                int h = (f0 >> 6) + half;
                dst = qbuf + (((size_t)(b_ * 12 + h) * 1024 + n0 + row2) << 6);
            } else {
                int h = ((f0 - 768) >> 6) + half;
                dst = kcbuf + (((size_t)(b_ * 12 + h) * 1056 + 16 + n0 + row2) << 6);
            }
#pragma unroll
            for (int c = 0; c < 8; ++c)
                *reinterpret_cast<short8*>(dst + c * 8) =
                    *reinterpret_cast<const short8*>(src + c * 8);
        } else {
            int fv = f0 - 1536 + row2;
            int h = fv >> 6, d = fv & 63;
            unsigned short* dst = vtbuf + ((size_t)(b_ * 12 + h) * 64 + d) * 1056
                                  + 16 + n0 + half * 64;
#pragma unroll
            for (int c = 0; c < 8; ++c) {
                short8 v;
#pragma unroll
                for (int j = 0; j < 8; ++j)
                    v[j] = (short)SH[(half * 64 + c * 8 + j) * 136 + row2];
                *reinterpret_cast<short8*>(dst + c * 8) = v;
            }
        }
    }
#undef STG
#undef AS_
#undef BS_
}

// -------- flash attention: swapped-QK 32x32, K async-LDS dbuf, static softmax --------
__global__ __launch_bounds__(256) void attn_kernel(
    const unsigned short* __restrict__ q,   // [96][1024][64] (pre-scaled by D^-0.5*log2e)
    const unsigned short* __restrict__ kc,  // [96][1056][64]
    const unsigned short* __restrict__ vT,  // [96][64][1056]
    unsigned short* __restrict__ ao)        // [8][1024][768]
{
    __shared__ __align__(16) unsigned short OT[4][32 * 72];   // epilogue bounce
    __shared__ __align__(16) unsigned short KS[4][2][2048];   // per-wave K dbuf

    const int tid = threadIdx.x;
    const int w = tid >> 6, lane = tid & 63;
    const int ql = lane & 31;
    const int hi = lane >> 5;

    const int bid = (blockIdx.x & 7) * 96 + (blockIdx.x >> 3);
    const int head = bid >> 3;
    const int qt = (bid & 7) * 4 + w;
    const int b = head / 12, h = head % 12;

    const unsigned short* qp = q + ((size_t)head * 1024 + qt * 32) * 64;
    const unsigned short* kp = kc + (size_t)head * 1056 * 64;
    const unsigned short* vp = vT + (size_t)head * 64 * 1056;

    const int srow = lane >> 3;
    const int sce  = ((lane & 7) ^ srow) << 3;
    const int rsw  = (ql & 7) << 4;

    short8 qf[4];
#pragma unroll
    for (int ks = 0; ks < 4; ++ks)
        qf[ks] = *reinterpret_cast<const short8*>(qp + (size_t)ql * 64 + ks * 16 + hi * 8);

    // prologue: stage K tile 0
#pragma unroll
    for (int i = 0; i < 4; ++i)
        GLOAD_LDS16(kp + (size_t)(i * 8 + srow) * 64 + sce,
                    (char*)&KS[w][0][0] + i * 1024);

    f32x16 o0 = (f32x16)0.f, o1 = (f32x16)0.f;
    const f32x16 fz = (f32x16)0.f;      // persistent zero C-operand
    float l = 0.f;                      // own-half partial; cross-half at end

    for (int t = 0; t < 33; ++t) {
        const int kbase = t * 32;
        const char* kcur = (const char*)&KS[w][t & 1][0];

        if (t < 32) {
            char* knx = (char*)&KS[w][(t & 1) ^ 1][0];
            const unsigned short* ksrc = kp + (size_t)(kbase + 32) * 64;
#pragma unroll
            for (int i = 0; i < 4; ++i)
                GLOAD_LDS16(ksrc + (size_t)(i * 8 + srow) * 64 + sce, knx + i * 1024);
            asm volatile("s_waitcnt vmcnt(4)" ::: "memory");
        } else {
            asm volatile("s_waitcnt vmcnt(0)" ::: "memory");
        }

        // ---- S^T = K·Q^T over D=64 (4 mfma); first uses persistent zero C ----
        f32x16 s;
        __builtin_amdgcn_s_setprio(1);
        {
            short8 kf = *reinterpret_cast<const short8*>(kcur + ql * 128 + ((hi * 16) ^ rsw));
            s = __builtin_amdgcn_mfma_f32_32x32x16_bf16(kf, qf[0], fz, 0, 0, 0);
        }
#pragma unroll
        for (int ks = 1; ks < 4; ++ks) {
            short8 kf = *reinterpret_cast<const short8*>(
                kcur + ql * 128 + ((ks * 32 + hi * 16) ^ rsw));
            s = __builtin_amdgcn_mfma_f32_32x32x16_bf16(kf, qf[ks], s, 0, 0, 0);
        }
        __builtin_amdgcn_s_setprio(0);

        if (t == 32) {   // keys 1040..1055 invalid -> regs 8..15
#pragma unroll
            for (int r = 8; r < 16; ++r) s[r] = -1e30f;
        }

        // ---- static softmax: p = 2^s via raw v_exp_f32; scalar adds ----
        float p[16];
#pragma unroll
        for (int r = 0; r < 16; ++r) p[r] = fexp2(s[r]);
        float ts = 0.f;
#pragma unroll
        for (int r = 0; r < 16; ++r) ts += p[r];
        l += ts;

        // ---- P -> bf16 B-fragments: cvt_pk + permlane32_swap ----
        int w0 = cvt_pk_bf16(p[0],  p[1]),  w1 = cvt_pk_bf16(p[2],  p[3]);
        int w2 = cvt_pk_bf16(p[4],  p[5]),  w3 = cvt_pk_bf16(p[6],  p[7]);
        int w4 = cvt_pk_bf16(p[8],  p[9]),  w5 = cvt_pk_bf16(p[10], p[11]);
        int w6 = cvt_pk_bf16(p[12], p[13]), w7 = cvt_pk_bf16(p[14], p[15]);
        PSWAP(w0, w2); PSWAP(w1, w3); PSWAP(w4, w6); PSWAP(w5, w7);
        i32x4 pw0, pw1;
        pw0[0] = w0; pw0[1] = w1; pw0[2] = w2; pw0[3] = w3;
        pw1[0] = w4; pw1[1] = w5; pw1[2] = w6; pw1[3] = w7;
        short8 pf0 = __builtin_bit_cast(short8, pw0);
        short8 pf1 = __builtin_bit_cast(short8, pw1);

        // ---- O^T += V^T · P^T (4 mfma), V direct from global ----
        short8 vf00 = *reinterpret_cast<const short8*>(vp + (size_t)ql * 1056 + kbase + hi * 8);
        short8 vf01 = *reinterpret_cast<const short8*>(vp + (size_t)ql * 1056 + kbase + 16 + hi * 8);
        short8 vf10 = *reinterpret_cast<const short8*>(vp + (size_t)(32 + ql) * 1056 + kbase + hi * 8);
        short8 vf11 = *reinterpret_cast<const short8*>(vp + (size_t)(32 + ql) * 1056 + kbase + 16 + hi * 8);
        __builtin_amdgcn_s_setprio(1);
        o0 = __builtin_amdgcn_mfma_f32_32x32x16_bf16(vf00, pf0, o0, 0, 0, 0);
        o0 = __builtin_amdgcn_mfma_f32_32x32x16_bf16(vf01, pf1, o0, 0, 0, 0);
        o1 = __builtin_amdgcn_mfma_f32_32x32x16_bf16(vf10, pf0, o1, 0, 0, 0);
        o1 = __builtin_amdgcn_mfma_f32_32x32x16_bf16(vf11, pf1, o1, 0, 0, 0);
        __builtin_amdgcn_s_setprio(0);
    }

    // ---- cross-half l reduce (deferred), then epilogue bounce ----
    l += __shfl_xor(l, 32);
    const float rinv = 1.f / l;
    o0 *= rinv;
    o1 *= rinv;
    unsigned short* ow = &OT[w][0];
#pragma unroll
    for (int r = 0; r < 16; r += 2) {
        int d = (r & 3) + 8 * (r >> 2) + 4 * hi;
        unsigned v0 = (unsigned)f2b(o0[r]) | ((unsigned)f2b(o0[r + 1]) << 16);
        *reinterpret_cast<unsigned*>(ow + ql * 72 + d) = v0;
        unsigned v1 = (unsigned)f2b(o1[r]) | ((unsigned)f2b(o1[r + 1]) << 16);
        *reinterpret_cast<unsigned*>(ow + ql * 72 + 32 + d) = v1;
    }
    LGKM0;
    __builtin_amdgcn_sched_barrier(0);
    const int row2 = lane >> 1, half = lane & 1;
    unsigned short* dst = ao + ((size_t)b * 1024 + qt * 32 + row2) * 768 + h * 64 + half * 32;
    const unsigned short* src = ow + row2 * 72 + half * 32;
#pragma unroll
    for (int c = 0; c < 4; ++c)
        *reinterpret_cast<short8*>(dst + c * 8) =
            *reinterpret_cast<const short8*>(src + c * 8);
}

extern "C" void kernel_launch(void* const* d_in, const int* in_sizes, int n_in,
                              void* d_out, int out_size, void* d_ws, size_t ws_size,
                              hipStream_t stream) {
    const float* x        = (const float*)d_in[0];
    const float* qkv_w    = (const float*)d_in[1];
    const float* qkv_b    = (const float*)d_in[2];
    const float* proj_w   = (const float*)d_in[3];
    const float* proj_b   = (const float*)d_in[4];
    const float* prefix_k = (const float*)d_in[5];
    const float* prefix_v = (const float*)d_in[6];
    float* out = (float*)d_out;

    char* ws = (char*)d_ws;
    unsigned short* xb   = (unsigned short*)(ws);               // 8192*768 bf16
    unsigned short* wqkv = (unsigned short*)(ws + 12582912);    // 2304*768
    unsigned short* wp   = (unsigned short*)(ws + 16121856);    // 768*768
    unsigned short* qb   = (unsigned short*)(ws + 17301504);    // 96*1024*64
    unsigned short* kcb  = (unsigned short*)(ws + 29884416);    // 96*1056*64
    unsigned short* vtb  = (unsigned short*)(ws + 42860544);    // 96*64*1056
    unsigned short* aob  = xb;                                  // reuse xb after QKV GEMM

    // fused converts: x (1572864 f4), qkv_w (442368 f4), proj_w (147456 f4)
    cvt3<<<2048, 256, 0, stream>>>(x, xb, 1572864, qkv_w, wqkv, 442368,
                                   proj_w, wp, 147456);
    prefill<<<768, 256, 0, stream>>>(prefix_k, prefix_v, kcb, vtb);

    // QKV: 64 m-tiles x 18 f-tiles = 1152 blocks (1152%8==0)
    gemm_dp<0, 18><<<1152, 256, 0, stream>>>(xb, wqkv, qkv_b, 8192, 2304, 768,
                                             qb, kcb, vtb, nullptr);
    attn_kernel<<<768, 256, 0, stream>>>(qb, kcb, vtb, aob);
    // proj: 64 m-tiles x 6 f-tiles = 384 blocks (384%8==0)
    gemm_dp<1, 6><<<384, 256, 0, stream>>>(aob, wp, proj_b, 8192, 768, 768,
                                           nullptr, nullptr, nullptr, out);
}

// Round 21
// 126.844 us; speedup vs baseline: 1.1934x; 1.0164x over previous
//
#include <hip/hip_runtime.h>

// Round 21 (attn only; GEMMs/cvt3/prefill frozen from R18/R20 best):
//   Block-shared K staging: all 4 waves share one head, so K tiles are staged
//   ONCE per block (wave w stages rows 8w..8w+7; 1 DMA/wave/tile, was 4).
//   Per tile: vmcnt(0) [own slice landed; V(t-1) already reg-drained] ->
//   s_barrier [all slices visible; buf (t+1)&1 free] -> issue K(t+1) -> compute.
//   K DMA issue and K L2 traffic both /4; KS LDS 32KB -> 8KB.
// Constants: B=8 N=1024 C=768 H=12 D=64 P=16; BH=96; padded KV MKV=1056.

typedef __attribute__((ext_vector_type(8))) short short8;
typedef __attribute__((ext_vector_type(4))) float f32x4;
typedef __attribute__((ext_vector_type(16))) float f32x16;
typedef __attribute__((ext_vector_type(4))) int i32x4;

#define GLOAD_LDS16(g, l)                                              \
    __builtin_amdgcn_global_load_lds(                                  \
        (const __attribute__((address_space(1))) void*)(g),            \
        (__attribute__((address_space(3))) void*)(l), 16, 0, 0)

#define GBAR  asm volatile("s_barrier" ::: "memory")
#define LGKM0 asm volatile("s_waitcnt lgkmcnt(0)" ::: "memory")
#define VMC4  asm volatile("s_waitcnt vmcnt(4)" ::: "memory")
#define VMC0  asm volatile("s_waitcnt vmcnt(0)" ::: "memory")
#define PSWAP(a, b) asm("v_permlane32_swap_b32 %0, %1" : "+v"(a), "+v"(b))

__device__ __forceinline__ unsigned short f2b(float f) {
    unsigned u = __builtin_bit_cast(unsigned, f);
    u = (u + 0x7fffu + ((u >> 16) & 1u)) >> 16;
    return (unsigned short)u;
}

__device__ __forceinline__ int cvt_pk_bf16(float lo, float hi) {
    int r;
    asm("v_cvt_pk_bf16_f32 %0, %1, %2" : "=v"(r) : "v"(lo), "v"(hi));
    return r;
}

__device__ __forceinline__ float fexp2(float x) {
    float r;
    asm("v_exp_f32 %0, %1" : "=v"(r) : "v"(x));
    return r;
}

// ---------- fused f32 -> bf16 convert for x, qkv_w, proj_w (1 launch) ----------
__global__ void cvt3(const float* __restrict__ a, unsigned short* __restrict__ ao, int na4,
                     const float* __restrict__ b, unsigned short* __restrict__ bo, int nb4,
                     const float* __restrict__ c, unsigned short* __restrict__ co, int nc4) {
    int total = na4 + nb4 + nc4;
    int i = blockIdx.x * blockDim.x + threadIdx.x;
    int stride = gridDim.x * blockDim.x;
    for (; i < total; i += stride) {
        const float* src; unsigned short* dst; int j;
        if (i < na4)            { src = a; dst = ao; j = i; }
        else if (i < na4 + nb4) { src = b; dst = bo; j = i - na4; }
        else                    { src = c; dst = co; j = i - na4 - nb4; }
        float4 v = reinterpret_cast<const float4*>(src)[j];
        ushort4 o;
        o.x = f2b(v.x); o.y = f2b(v.y); o.z = f2b(v.z); o.w = f2b(v.w);
        reinterpret_cast<ushort4*>(dst)[j] = o;
    }
}

// ------------- prefix K/V prefill + pad-row zeroing ----------------
__global__ void prefill(const float* __restrict__ pk, const float* __restrict__ pv,
                        unsigned short* __restrict__ kc, unsigned short* __restrict__ vT) {
    int idx = blockIdx.x * 256 + threadIdx.x;   // 96*32*64 total
    int d  = idx & 63;
    int j  = (idx >> 6) & 31;
    int bh = idx >> 11;
    if (bh >= 96) return;
    int h = bh % 12;
    if (j < 16) {
        kc[((size_t)bh * 1056 + j) * 64 + d]  = f2b(pk[j * 768 + h * 64 + d]);
        vT[((size_t)bh * 64 + d) * 1056 + j]  = f2b(pv[j * 768 + h * 64 + d]);
    } else {
        int row = 1040 + (j - 16);
        kc[((size_t)bh * 1056 + row) * 64 + d] = 0;
        vT[((size_t)bh * 64 + d) * 1056 + row] = 0;
    }
}

// ------- GEMM: BK=32 ring-3, counted vmcnt(4), 48KB LDS, 3 blocks/CU -------
template<int MODE, int FT>
__global__ __launch_bounds__(256, 3) void gemm_dp(
    const unsigned short* __restrict__ A,
    const unsigned short* __restrict__ W,
    const float* __restrict__ bias,
    int M, int F, int K,
    unsigned short* __restrict__ qbuf,
    unsigned short* __restrict__ kcbuf,
    unsigned short* __restrict__ vtbuf,
    float* __restrict__ fout)
{
    __shared__ __align__(16) unsigned short SH[24576];   // 48KB
#define AS_(s) (SH + (s) * 4096)
#define BS_(s) (SH + 12288 + (s) * 4096)

    const int tid = threadIdx.x;
    const int bid = (blockIdx.x & 7) * (gridDim.x >> 3) + (blockIdx.x >> 3);
    const int m0 = (bid / FT) * 128;
    const int f0 = (bid % FT) * 128;
    const int wid = tid >> 6, lane = tid & 63;
    const int wr = wid >> 1, wc = wid & 1;
    const int lo = lane & 15, hi = lane >> 4;
    const int rdsw = ((hi ^ (lo & 3)) << 4);

#define STG(SLOT, KT)                                                            \
    { _Pragma("unroll") for (int r_ = 0; r_ < 2; ++r_) {                         \
        int id_ = r_ * 256 + tid; int row_ = id_ >> 2;                           \
        int sc_ = (((id_ & 3) ^ (row_ & 3)) << 3);                               \
        GLOAD_LDS16(A + (size_t)(m0 + row_) * K + (KT) * 32 + sc_,               \
                    (char*)AS_(SLOT) + id_ * 16);                                \
        GLOAD_LDS16(W + (size_t)(f0 + row_) * K + (KT) * 32 + sc_,               \
                    (char*)BS_(SLOT) + id_ * 16);                                \
    } }

    f32x4 acc[4][4];
#pragma unroll
    for (int i = 0; i < 4; ++i)
#pragma unroll
        for (int j = 0; j < 4; ++j) acc[i][j] = (f32x4)0.f;

    const int nt = K >> 5;   // 24

    STG(0, 0);
    STG(1, 1);
    VMC4; GBAR;

    int slot = 0, nslot = 2;
    for (int t = 0; t < nt; ++t) {
        if (t + 2 < nt) {
            STG(nslot, t + 2);
            nslot = (nslot == 2) ? 0 : nslot + 1;
        }

        short8 av[4], bv[4];
#pragma unroll
        for (int i = 0; i < 4; ++i) {
            av[i] = *reinterpret_cast<const short8*>(
                (const char*)AS_(slot) + (wr * 64 + i * 16 + lo) * 64 + rdsw);
            bv[i] = *reinterpret_cast<const short8*>(
                (const char*)BS_(slot) + (wc * 64 + i * 16 + lo) * 64 + rdsw);
        }
        slot = (slot == 2) ? 0 : slot + 1;

        __builtin_amdgcn_s_setprio(1);
#pragma unroll
        for (int i = 0; i < 4; ++i)
#pragma unroll
            for (int j = 0; j < 4; ++j)
                acc[i][j] = __builtin_amdgcn_mfma_f32_16x16x32_bf16(
                    av[i], bv[j], acc[i][j], 0, 0, 0);
        __builtin_amdgcn_s_setprio(0);

        if (t + 1 < nt) {
            if (t + 2 < nt) { VMC4; }
            else            { VMC0; }
            GBAR;
        }
    }

    if (MODE == 1) {
#pragma unroll
        for (int mi = 0; mi < 4; ++mi) {
#pragma unroll
            for (int ni = 0; ni < 4; ++ni) {
                int f = f0 + wc * 64 + ni * 16 + lo;
                float bv2 = bias[f];
#pragma unroll
                for (int r = 0; r < 4; ++r) {
                    int m = m0 + wr * 64 + mi * 16 + hi * 4 + r;
                    fout[(size_t)m * F + f] = acc[mi][ni][r] + bv2;
                }
            }
        }
    } else {
        __syncthreads();
        // Q scale = D^-0.5 * log2(e): QK^T emits log2-domain scores (static softmax)
        const float sc = (f0 < 768) ? 0.1803368801111204f : 1.f;
#pragma unroll
        for (int mi = 0; mi < 4; ++mi) {
#pragma unroll
            for (int ni = 0; ni < 4; ++ni) {
                int fc = wc * 64 + ni * 16 + lo;
                float bv2 = bias[f0 + fc];
#pragma unroll
                for (int r = 0; r < 4; ++r) {
                    int mr = wr * 64 + mi * 16 + hi * 4 + r;
                    SH[mr * 136 + fc] = f2b((acc[mi][ni][r] + bv2) * sc);
                }
            }
        }
        __syncthreads();

        const int row2 = tid >> 1, half = tid & 1;
        const int b_ = m0 >> 10, n0 = m0 & 1023;
        if (f0 < 1536) {
            const unsigned short* src = SH + row2 * 136 + half * 64;
            unsigned short* dst;
            if (f0 < 768) {
                int h = (f0 >> 6) + half;
                dst = qbuf + (((size_t)(b_ * 12 + h) * 1024 + n0 + row2) << 6);
            } else {
                int h = ((f0 - 768) >> 6) + half;
                dst = kcbuf + (((size_t)(b_ * 12 + h) * 1056 + 16 + n0 + row2) << 6);
            }
#pragma unroll
            for (int c = 0; c < 8; ++c)
                *reinterpret_cast<short8*>(dst + c * 8) =
                    *reinterpret_cast<const short8*>(src + c * 8);
        } else {
            int fv = f0 - 1536 + row2;
            int h = fv >> 6, d = fv & 63;
            unsigned short* dst = vtbuf + ((size_t)(b_ * 12 + h) * 64 + d) * 1056
                                  + 16 + n0 + half * 64;
#pragma unroll
            for (int c = 0; c < 8; ++c) {
                short8 v;
#pragma unroll
                for (int j = 0; j < 8; ++j)
                    v[j] = (short)SH[(half * 64 + c * 8 + j) * 136 + row2];
                *reinterpret_cast<short8*>(dst + c * 8) = v;
            }
        }
    }
#undef STG
#undef AS_
#undef BS_
}

// -------- flash attention: swapped-QK 32x32, block-shared K staging --------
__global__ __launch_bounds__(256) void attn_kernel(
    const unsigned short* __restrict__ q,   // [96][1024][64] (pre-scaled by D^-0.5*log2e)
    const unsigned short* __restrict__ kc,  // [96][1056][64]
    const unsigned short* __restrict__ vT,  // [96][64][1056]
    unsigned short* __restrict__ ao)        // [8][1024][768]
{
    __shared__ __align__(16) unsigned short OT[4][32 * 72];   // epilogue bounce
    __shared__ __align__(16) unsigned short KS[2][2048];      // block-shared K dbuf (8KB)

    const int tid = threadIdx.x;
    const int w = tid >> 6, lane = tid & 63;
    const int ql = lane & 31;
    const int hi = lane >> 5;

    const int bid = (blockIdx.x & 7) * 96 + (blockIdx.x >> 3);
    const int head = bid >> 3;
    const int qt = (bid & 7) * 4 + w;
    const int b = head / 12, h = head % 12;

    const unsigned short* qp = q + ((size_t)head * 1024 + qt * 32) * 64;
    const unsigned short* kp = kc + (size_t)head * 1056 * 64;
    const unsigned short* vp = vT + (size_t)head * 64 * 1056;

    // shared staging: wave w covers rows 8w + (lane>>3); slot (lane&7) pre-swizzled
    const int srow = lane >> 3;
    const int sce  = ((lane & 7) ^ srow) << 3;
    const int rsw  = (ql & 7) << 4;
    const int krow = w * 8 + srow;                  // global K row within tile

    short8 qf[4];
#pragma unroll
    for (int ks = 0; ks < 4; ++ks)
        qf[ks] = *reinterpret_cast<const short8*>(qp + (size_t)ql * 64 + ks * 16 + hi * 8);

    // prologue: block cooperatively stages K tile 0 (1 DMA per wave)
    GLOAD_LDS16(kp + (size_t)krow * 64 + sce, (char*)&KS[0][0] + w * 1024);

    f32x16 o0 = (f32x16)0.f, o1 = (f32x16)0.f;
    const f32x16 fz = (f32x16)0.f;      // persistent zero C-operand
    float l = 0.f;

    for (int t = 0; t < 33; ++t) {
        const int kbase = t * 32;
        const char* kcur = (const char*)&KS[t & 1][0];

        // own K(t) slice landed (only op outstanding; V(t-1) reg-drained)
        VMC0;
        // all waves' slices visible; buffer (t+1)&1 free (everyone past t-1)
        GBAR;
        if (t < 32) {
            GLOAD_LDS16(kp + (size_t)(kbase + 32 + krow) * 64 + sce,
                        (char*)&KS[(t & 1) ^ 1][0] + w * 1024);
        }

        // ---- S^T = K·Q^T over D=64 (4 mfma); first uses persistent zero C ----
        f32x16 s;
        __builtin_amdgcn_s_setprio(1);
        {
            short8 kf = *reinterpret_cast<const short8*>(kcur + ql * 128 + ((hi * 16) ^ rsw));
            s = __builtin_amdgcn_mfma_f32_32x32x16_bf16(kf, qf[0], fz, 0, 0, 0);
        }
#pragma unroll
        for (int ks = 1; ks < 4; ++ks) {
            short8 kf = *reinterpret_cast<const short8*>(
                kcur + ql * 128 + ((ks * 32 + hi * 16) ^ rsw));
            s = __builtin_amdgcn_mfma_f32_32x32x16_bf16(kf, qf[ks], s, 0, 0, 0);
        }
        __builtin_amdgcn_s_setprio(0);

        if (t == 32) {   // keys 1040..1055 invalid -> regs 8..15
#pragma unroll
            for (int r = 8; r < 16; ++r) s[r] = -1e30f;
        }

        // ---- static softmax: p = 2^s via raw v_exp_f32; scalar adds ----
        float p[16];
#pragma unroll
        for (int r = 0; r < 16; ++r) p[r] = fexp2(s[r]);
        float ts = 0.f;
#pragma unroll
        for (int r = 0; r < 16; ++r) ts += p[r];
        l += ts;

        // ---- P -> bf16 B-fragments: cvt_pk + permlane32_swap ----
        int w0 = cvt_pk_bf16(p[0],  p[1]),  w1 = cvt_pk_bf16(p[2],  p[3]);
        int w2 = cvt_pk_bf16(p[4],  p[5]),  w3 = cvt_pk_bf16(p[6],  p[7]);
        int w4 = cvt_pk_bf16(p[8],  p[9]),  w5 = cvt_pk_bf16(p[10], p[11]);
        int w6 = cvt_pk_bf16(p[12], p[13]), w7 = cvt_pk_bf16(p[14], p[15]);
        PSWAP(w0, w2); PSWAP(w1, w3); PSWAP(w4, w6); PSWAP(w5, w7);
        i32x4 pw0, pw1;
        pw0[0] = w0; pw0[1] = w1; pw0[2] = w2; pw0[3] = w3;
        pw1[0] = w4; pw1[1] = w5; pw1[2] = w6; pw1[3] = w7;
        short8 pf0 = __builtin_bit_cast(short8, pw0);
        short8 pf1 = __builtin_bit_cast(short8, pw1);

        // ---- O^T += V^T · P^T (4 mfma), V direct from global ----
        short8 vf00 = *reinterpret_cast<const short8*>(vp + (size_t)ql * 1056 + kbase + hi * 8);
        short8 vf01 = *reinterpret_cast<const short8*>(vp + (size_t)ql * 1056 + kbase + 16 + hi * 8);
        short8 vf10 = *reinterpret_cast<const short8*>(vp + (size_t)(32 + ql) * 1056 + kbase + hi * 8);
        short8 vf11 = *reinterpret_cast<const short8*>(vp + (size_t)(32 + ql) * 1056 + kbase + 16 + hi * 8);
        __builtin_amdgcn_s_setprio(1);
        o0 = __builtin_amdgcn_mfma_f32_32x32x16_bf16(vf00, pf0, o0, 0, 0, 0);
        o0 = __builtin_amdgcn_mfma_f32_32x32x16_bf16(vf01, pf1, o0, 0, 0, 0);
        o1 = __builtin_amdgcn_mfma_f32_32x32x16_bf16(vf10, pf0, o1, 0, 0, 0);
        o1 = __builtin_amdgcn_mfma_f32_32x32x16_bf16(vf11, pf1, o1, 0, 0, 0);
        __builtin_amdgcn_s_setprio(0);
    }

    // ---- cross-half l reduce (deferred), then epilogue bounce ----
    l += __shfl_xor(l, 32);
    const float rinv = 1.f / l;
    o0 *= rinv;
    o1 *= rinv;
    unsigned short* ow = &OT[w][0];
#pragma unroll
    for (int r = 0; r < 16; r += 2) {
        int d = (r & 3) + 8 * (r >> 2) + 4 * hi;
        unsigned v0 = (unsigned)f2b(o0[r]) | ((unsigned)f2b(o0[r + 1]) << 16);
        *reinterpret_cast<unsigned*>(ow + ql * 72 + d) = v0;
        unsigned v1 = (unsigned)f2b(o1[r]) | ((unsigned)f2b(o1[r + 1]) << 16);
        *reinterpret_cast<unsigned*>(ow + ql * 72 + 32 + d) = v1;
    }
    LGKM0;
    __builtin_amdgcn_sched_barrier(0);
    const int row2 = lane >> 1, half = lane & 1;
    unsigned short* dst = ao + ((size_t)b * 1024 + qt * 32 + row2) * 768 + h * 64 + half * 32;
    const unsigned short* src = ow + row2 * 72 + half * 32;
#pragma unroll
    for (int c = 0; c < 4; ++c)
        *reinterpret_cast<short8*>(dst + c * 8) =
            *reinterpret_cast<const short8*>(src + c * 8);
}

extern "C" void kernel_launch(void* const* d_in, const int* in_sizes, int n_in,
                              void* d_out, int out_size, void* d_ws, size_t ws_size,
                              hipStream_t stream) {
    const float* x        = (const float*)d_in[0];
    const float* qkv_w    = (const float*)d_in[1];
    const float* qkv_b    = (const float*)d_in[2];
    const float* proj_w   = (const float*)d_in[3];
    const float* proj_b   = (const float*)d_in[4];
    const float* prefix_k = (const float*)d_in[5];
    const float* prefix_v = (const float*)d_in[6];
    float* out = (float*)d_out;

    char* ws = (char*)d_ws;
    unsigned short* xb   = (unsigned short*)(ws);               // 8192*768 bf16
    unsigned short* wqkv = (unsigned short*)(ws + 12582912);    // 2304*768
    unsigned short* wp   = (unsigned short*)(ws + 16121856);    // 768*768
    unsigned short* qb   = (unsigned short*)(ws + 17301504);    // 96*1024*64
    unsigned short* kcb  = (unsigned short*)(ws + 29884416);    // 96*1056*64
    unsigned short* vtb  = (unsigned short*)(ws + 42860544);    // 96*64*1056
    unsigned short* aob  = xb;                                  // reuse xb after QKV GEMM

    // fused converts: x (1572864 f4), qkv_w (442368 f4), proj_w (147456 f4)
    cvt3<<<2048, 256, 0, stream>>>(x, xb, 1572864, qkv_w, wqkv, 442368,
                                   proj_w, wp, 147456);
    prefill<<<768, 256, 0, stream>>>(prefix_k, prefix_v, kcb, vtb);

    // QKV: 64 m-tiles x 18 f-tiles = 1152 blocks (1152%8==0)
    gemm_dp<0, 18><<<1152, 256, 0, stream>>>(xb, wqkv, qkv_b, 8192, 2304, 768,
                                             qb, kcb, vtb, nullptr);
    attn_kernel<<<768, 256, 0, stream>>>(qb, kcb, vtb, aob);
    // proj: 64 m-tiles x 6 f-tiles = 384 blocks (384%8==0)
    gemm_dp<1, 6><<<384, 256, 0, stream>>>(aob, wp, proj_b, 8192, 768, 768,
                                           nullptr, nullptr, nullptr, out);
}